// Round 4
// baseline (290.142 us; speedup 1.0000x reference)
//
#include <hip/hip_runtime.h>

// out = joints @ R + t, R = RX(roll) @ RY(pitch) @ RZ(yaw), per reference.
// Streaming memory-bound op: 169 MB in + 169 MB out.
//
// v5 reasoning (v1 strided / v3 strided / v4 LDS-dense all ~98-103 us ->
// access pattern is NOT the limiter):
//  - rocprof: FETCH 85 MB (half of input; other half L3-hit), WRITE 170 MB,
//    HBM ~2.5 TB/s, VALU 2%, LDS conflicts 0. Nothing on-chip saturated.
//    The one reducible quantity is FETCH: input (169 MB) fits L3 (256 MB),
//    but our write-allocate output stream (169 MB/iter through L3) evicts
//    half of it every iteration.
//  - Fix: NONTEMPORAL stores on the DENSE store phase. v2 proved nt +
//    96B-stride = 2.3x amplification (partial sectors); v4's dense phase
//    stores 1 KB contiguous per wave-instruction = full 64B sectors, so
//    nt is amplification-free here and keeps the output from allocating
//    in L2/L3 -> input stays resident -> FETCH -> ~0.
//  - LDS block shrunk to 12 KB (3 float4/thread): stride-3 f4 fragment
//    reads are coprime with the 8 f4 bank-columns -> conflict-free with
//    NO swizzle; 8 blocks/CU resident (32 waves/CU) vs v4's 6 blocks.
//  - KEEP __sinf/__cosf, regular (cached) loads.

using f4 = __attribute__((ext_vector_type(4))) float;

#define BLOCK 256
#define F4_PER_THREAD 3
#define F4_PER_BLOCK (BLOCK * F4_PER_THREAD)      // 768 float4 = 12 KB
#define PTS_PER_BLOCK ((F4_PER_BLOCK * 4) / 3)    // 1024 points (exact)

__global__ __launch_bounds__(BLOCK, 8) void Transform_38723425141290_kernel(
    const float* __restrict__ joints,
    const float* __restrict__ orient,
    const float* __restrict__ trans,
    float* __restrict__ out,
    long long n_points)
{
    __shared__ f4 lds[F4_PER_BLOCK];

    // --- rotation matrix (wave-uniform; tiny cached reads) ---
    const float roll = orient[0], pitch = orient[1], yaw = orient[2];
    const float sr = __sinf(roll),  cr = __cosf(roll);
    const float sp = __sinf(pitch), cp = __cosf(pitch);
    const float sy = __sinf(yaw),   cy = __cosf(yaw);

    const float R00 = cp * cy;
    const float R01 = -cp * sy;
    const float R02 = sp;
    const float R10 = sr * sp * cy + cr * sy;
    const float R11 = cr * cy - sr * sp * sy;
    const float R12 = -sr * cp;
    const float R20 = sr * sy - cr * sp * cy;
    const float R21 = cr * sp * sy + sr * cy;
    const float R22 = cr * cp;

    const float tx = trans[0], ty = trans[1], tz = trans[2];

    const int tid = threadIdx.x;
    const long long blk = blockIdx.x;

    if ((blk + 1) * (long long)PTS_PER_BLOCK <= n_points) {
        // ---- fast path: full 1024-point region ----
        const long long f4_base = blk * (long long)F4_PER_BLOCK;
        const f4* jp = reinterpret_cast<const f4*>(joints) + f4_base;

        // dense, cached staging loads (input should stay L3-resident)
        lds[0 * BLOCK + tid] = jp[0 * BLOCK + tid];
        lds[1 * BLOCK + tid] = jp[1 * BLOCK + tid];
        lds[2 * BLOCK + tid] = jp[2 * BLOCK + tid];
        __syncthreads();

        // each thread owns 3 consecutive float4s = 12 floats = 4 points
        // (stride-3 f4 reads: 3 coprime with 8 bank-columns -> conflict-free)
        f4 a = lds[tid * 3 + 0];
        f4 b = lds[tid * 3 + 1];
        f4 c = lds[tid * 3 + 2];

        f4 o0, o1, o2;
        #define ROT(x, y, z, ox, oy, oz)              \
            ox = x * R00 + y * R10 + z * R20 + tx;    \
            oy = x * R01 + y * R11 + z * R21 + ty;    \
            oz = x * R02 + y * R12 + z * R22 + tz;

        ROT(a.x, a.y, a.z, o0.x, o0.y, o0.z)
        ROT(a.w, b.x, b.y, o0.w, o1.x, o1.y)
        ROT(b.z, b.w, c.x, o1.z, o1.w, o2.x)
        ROT(c.y, c.z, c.w, o2.y, o2.z, o2.w)
        #undef ROT

        // thread-private slots: no barrier needed between read and write
        lds[tid * 3 + 0] = o0;
        lds[tid * 3 + 1] = o1;
        lds[tid * 3 + 2] = o2;
        __syncthreads();

        // dense NONTEMPORAL stores: each wave-instr covers 1 KB contiguous
        // (full 64B sectors -> no partial-line amplification), bypasses
        // L2/L3 allocation so the input stays cache-resident.
        f4* op = reinterpret_cast<f4*>(out) + f4_base;
        __builtin_nontemporal_store(lds[0 * BLOCK + tid], op + 0 * BLOCK + tid);
        __builtin_nontemporal_store(lds[1 * BLOCK + tid], op + 1 * BLOCK + tid);
        __builtin_nontemporal_store(lds[2 * BLOCK + tid], op + 2 * BLOCK + tid);
    } else {
        // ---- tail block: scalar per-point (dead for this shape) ----
        for (long long p = blk * (long long)PTS_PER_BLOCK + tid; p < n_points;
             p += BLOCK) {
            const float x = joints[p * 3 + 0];
            const float y = joints[p * 3 + 1];
            const float z = joints[p * 3 + 2];
            out[p * 3 + 0] = x * R00 + y * R10 + z * R20 + tx;
            out[p * 3 + 1] = x * R01 + y * R11 + z * R21 + ty;
            out[p * 3 + 2] = x * R02 + y * R12 + z * R22 + tz;
        }
    }
}

extern "C" void kernel_launch(void* const* d_in, const int* in_sizes, int n_in,
                              void* d_out, int out_size, void* d_ws, size_t ws_size,
                              hipStream_t stream) {
    const float* joints = (const float*)d_in[0];
    const float* orient = (const float*)d_in[1];
    const float* trans  = (const float*)d_in[2];
    float* out = (float*)d_out;

    const long long n_floats = (long long)in_sizes[0];
    const long long n_points = n_floats / 3;

    const long long grid =
        (n_points + PTS_PER_BLOCK - 1) / PTS_PER_BLOCK;

    Transform_38723425141290_kernel<<<dim3((unsigned)grid), dim3(BLOCK), 0, stream>>>(
        joints, orient, trans, out, n_points);
}